// Round 1
// baseline (449.545 us; speedup 1.0000x reference)
//
#include <hip/hip_runtime.h>
#include <math.h>

// SE layer: B=16, C=256, H=W=128. Only batch 0 is gated (reference uses s[0]).
#define HW    16384        // 128*128
#define CCH   256
#define HID   16

// ---- Kernel 1: per-channel mean of batch 0 (256 blocks, one per channel) ----
__global__ void se_pool(const float* __restrict__ x, float* __restrict__ y) {
    const int c = blockIdx.x;
    const float4* p = (const float4*)(x + (size_t)c * HW);
    float sum = 0.f;
    for (int i = threadIdx.x; i < HW / 4; i += blockDim.x) {
        float4 v = p[i];
        sum += (v.x + v.y) + (v.z + v.w);
    }
    // wave-64 shuffle reduce
    #pragma unroll
    for (int off = 32; off > 0; off >>= 1)
        sum += __shfl_down(sum, off, 64);
    __shared__ float wsum[4];
    const int lane = threadIdx.x & 63;
    const int wave = threadIdx.x >> 6;
    if (lane == 0) wsum[wave] = sum;
    __syncthreads();
    if (threadIdx.x == 0) {
        float s = (wsum[0] + wsum[1]) + (wsum[2] + wsum[3]);
        y[c] = s * (1.0f / (float)HW);
    }
}

// ---- Kernel 2: tiny MLP 256->16->256 + sigmoid (1 block of 256 threads) ----
__global__ void se_mlp(const float* __restrict__ y,
                       const float* __restrict__ w1, const float* __restrict__ b1,
                       const float* __restrict__ w2, const float* __restrict__ b2,
                       float* __restrict__ s) {
    __shared__ float ysh[CCH];
    __shared__ float h[HID];
    const int t = threadIdx.x;
    ysh[t] = y[t];
    __syncthreads();
    if (t < HID) {
        float acc = b1[t];
        const float* wr = w1 + t * CCH;
        #pragma unroll 8
        for (int c = 0; c < CCH; ++c) acc = fmaf(ysh[c], wr[c], acc);
        h[t] = fmaxf(acc, 0.f);
    }
    __syncthreads();
    float acc = b2[t];
    const float* wr2 = w2 + t * HID;
    #pragma unroll
    for (int j = 0; j < HID; ++j) acc = fmaf(h[j], wr2[j], acc);
    s[t] = 1.0f / (1.0f + __expf(-acc));
}

// ---- Kernel 3: out = x, with batch 0 channels scaled by s[c] ----
__global__ void se_scale(const float* __restrict__ x, const float* __restrict__ s,
                         float* __restrict__ out) {
    const float4* __restrict__ xin = (const float4*)x;
    float4* __restrict__ o = (float4*)out;
    const size_t n4 = (size_t)16 * CCH * (HW / 4);   // 16,777,216 float4s total
    const size_t b0 = (size_t)CCH * (HW / 4);        //  1,048,576 float4s in batch 0
    size_t i = (size_t)blockIdx.x * blockDim.x + threadIdx.x;
    const size_t stride = (size_t)gridDim.x * blockDim.x;
    for (; i < n4; i += stride) {
        float4 v = xin[i];
        if (i < b0) {
            // 4096 float4s per channel -> channel = i >> 12 (uniform within vec)
            const float g = s[i >> 12];
            v.x *= g; v.y *= g; v.z *= g; v.w *= g;
        }
        o[i] = v;
    }
}

extern "C" void kernel_launch(void* const* d_in, const int* in_sizes, int n_in,
                              void* d_out, int out_size, void* d_ws, size_t ws_size,
                              hipStream_t stream) {
    const float* x  = (const float*)d_in[0];
    const float* w1 = (const float*)d_in[1];
    const float* b1 = (const float*)d_in[2];
    const float* w2 = (const float*)d_in[3];
    const float* b2 = (const float*)d_in[4];
    float* out = (float*)d_out;

    float* y = (float*)d_ws;      // 256 floats: pooled means of batch 0
    float* s = y + CCH;           // 256 floats: sigmoid gates

    se_pool<<<CCH, 256, 0, stream>>>(x, y);
    se_mlp<<<1, 256, 0, stream>>>(y, w1, b1, w2, b2, s);
    // 16384 blocks x 256 threads: each thread moves 4 float4 (64 B each way)
    se_scale<<<16384, 256, 0, stream>>>(x, s, out);
}